// Round 2
// baseline (46.247 us; speedup 1.0000x reference)
//
#include <hip/hip_runtime.h>
#include <hip/hip_bf16.h>

// Problem constants
#define BB 64
#define CC 512
#define DD 256
// loss = mean_{b,c} [ log(sum_k exp(2*S_bck)) - 2*S_bcc ],  S = Vn . Tn^T

typedef __attribute__((ext_vector_type(8))) short bf16x8;  // 8 bf16 = 4 VGPRs
typedef __attribute__((ext_vector_type(4))) float f32x4;

__device__ inline unsigned short f2bf(float f) {
    __hip_bfloat16 h = __float2bfloat16(f);
    union { __hip_bfloat16 h; unsigned short u; } cv;
    cv.h = h;
    return cv.u;
}

// ---------------- Pass 1: L2-normalize rows (fp32 in -> bf16 out) ----------------
// one wave per 256-elem row; 4 rows per 256-thread block
__global__ __launch_bounds__(256) void norm_rows(const float* __restrict__ in,
                                                 unsigned short* __restrict__ out) {
    const int row  = blockIdx.x * 4 + (threadIdx.x >> 6);
    const int lane = threadIdx.x & 63;
    const float4 x = reinterpret_cast<const float4*>(in)[(size_t)row * 64 + lane];
    float ss = x.x * x.x + x.y * x.y + x.z * x.z + x.w * x.w;
#pragma unroll
    for (int off = 32; off; off >>= 1) ss += __shfl_xor(ss, off);
    const float r = 1.0f / fmaxf(sqrtf(ss), 1e-12f);
    ushort4 o;
    o.x = f2bf(x.x * r);
    o.y = f2bf(x.y * r);
    o.z = f2bf(x.z * r);
    o.w = f2bf(x.w * r);
    reinterpret_cast<ushort4*>(out)[(size_t)row * 64 + lane] = o;
}

// ---------------- Pass 2: batched GEMM + fused contrastive-loss epilogue ----------------
// grid = 256 blocks: blockIdx = b*4 + rb.  Block computes rows [rb*128, rb*128+128) of S_b
// (S = Vn_b (512x256) . Tn_b^T), sweeping 4 col-tiles of 128.
// LDS: As 64KB + Bs 64KB, both XOR-swizzled (byte ^= (row&7)<<4) to kill ds_read_b128 conflicts.
__global__ __launch_bounds__(256, 1) void gemm_loss(const unsigned short* __restrict__ Vn,
                                                    const unsigned short* __restrict__ Tn,
                                                    float* __restrict__ partials) {
    extern __shared__ char lds[];
    char* As = lds;           // 128 rows x 512 B
    char* Bs = lds + 65536;   // 128 rows x 512 B

    const int b    = blockIdx.x >> 2;
    const int rb   = blockIdx.x & 3;
    const int tid  = threadIdx.x;
    const int lane = tid & 63;
    const int wave = tid >> 6;
    const int wr   = wave >> 1;   // 2x2 wave grid, each wave owns 64x64 of the 128x128 tile
    const int wc   = wave & 1;
    const int g    = lane >> 4;   // k-group (0..3)
    const int ln   = lane & 15;

    // ---- stage A tile (Vn rows rb*128 .. +127, all K=256) : 64 KB ----
    {
        const float4* gA =
            reinterpret_cast<const float4*>(Vn + (size_t)b * (CC * DD) + (size_t)rb * 128 * DD);
#pragma unroll
        for (int it = 0; it < 16; ++it) {
            const int idx  = it * 256 + tid;   // float4 index
            const int p    = idx * 16;         // byte offset
            const int row  = p >> 9;
            const int bcol = p & 511;
            *reinterpret_cast<float4*>(As + row * 512 + (bcol ^ ((row & 7) << 4))) = gA[idx];
        }
    }

    float rs[4][4];  // rowsum of exp(2S) over this wave's columns, per (i-frag, reg r)
    float dg[4][4];  // diagonal 2*S term, per (i-frag, reg r)
#pragma unroll
    for (int i = 0; i < 4; ++i)
#pragma unroll
        for (int r = 0; r < 4; ++r) {
            rs[i][r] = 0.f;
            dg[i][r] = 0.f;
        }

    const f32x4 fzero = {0.f, 0.f, 0.f, 0.f};
    for (int ct = 0; ct < 4; ++ct) {
        __syncthreads();
        // ---- stage B tile (Tn rows ct*128 .. +127) : 64 KB ----
        const float4* gB =
            reinterpret_cast<const float4*>(Tn + (size_t)b * (CC * DD) + (size_t)ct * 128 * DD);
#pragma unroll
        for (int it = 0; it < 16; ++it) {
            const int idx  = it * 256 + tid;
            const int p    = idx * 16;
            const int row  = p >> 9;
            const int bcol = p & 511;
            *reinterpret_cast<float4*>(Bs + row * 512 + (bcol ^ ((row & 7) << 4))) = gB[idx];
        }
        __syncthreads();

        f32x4 acc[4][4];
#pragma unroll
        for (int i = 0; i < 4; ++i)
#pragma unroll
            for (int j = 0; j < 4; ++j) acc[i][j] = fzero;

#pragma unroll
        for (int kk = 0; kk < 8; ++kk) {
            const int bcol = kk * 64 + g * 16;  // byte offset of this lane's 8-bf16 k-chunk
            bf16x8 a[4], bbf[4];
#pragma unroll
            for (int i = 0; i < 4; ++i) {
                const int row = wr * 64 + i * 16 + ln;
                a[i] = *reinterpret_cast<const bf16x8*>(As + row * 512 + (bcol ^ ((row & 7) << 4)));
            }
#pragma unroll
            for (int j = 0; j < 4; ++j) {
                const int row = wc * 64 + j * 16 + ln;
                bbf[j] =
                    *reinterpret_cast<const bf16x8*>(Bs + row * 512 + (bcol ^ ((row & 7) << 4)));
            }
#pragma unroll
            for (int i = 0; i < 4; ++i)
#pragma unroll
                for (int j = 0; j < 4; ++j)
                    acc[i][j] =
                        __builtin_amdgcn_mfma_f32_16x16x32_bf16(a[i], bbf[j], acc[i][j], 0, 0, 0);
        }

        // ---- fused epilogue: exp(2*S) partial rowsum + diagonal grab ----
        // C/D layout: col = lane&15, row = (lane>>4)*4 + r  [within each 16x16 fragment]
        const int gcol_base = ct * 128 + wc * 64;
#pragma unroll
        for (int i = 0; i < 4; ++i) {
            const int grow_base = rb * 128 + wr * 64 + i * 16 + g * 4;  // + r
#pragma unroll
            for (int j = 0; j < 4; ++j) {
                const int gcol = gcol_base + j * 16 + ln;
#pragma unroll
                for (int r = 0; r < 4; ++r) {
                    const float s2 = acc[i][j][r] * 2.0f;  // sim / TEMPERATURE
                    rs[i][r] += __expf(s2);
                    if (gcol == grow_base + r) dg[i][r] += s2;
                }
            }
        }
    }

    // ---- per-row completion ----
    // Each row's 512 columns are split across the two wc-waves: combine the raw
    // exp-sums in LDS BEFORE taking log (log(A)+log(B) != log(A+B) was the bug).
    __syncthreads();  // all waves done reading the tiles; safe to reuse LDS
    float* vred = reinterpret_cast<float*>(lds);   // [128][2] partial exp-sums
    float* dred = vred + 256;                      // [128][2] partial diag terms
#pragma unroll
    for (int i = 0; i < 4; ++i)
#pragma unroll
        for (int r = 0; r < 4; ++r) {
            float v = rs[i][r];
            float d = dg[i][r];
#pragma unroll
            for (int m = 1; m < 16; m <<= 1) {  // reduce the 16 column-lanes (same g)
                v += __shfl_xor(v, m);
                d += __shfl_xor(d, m);
            }
            if (ln == 0) {
                const int rl = wr * 64 + i * 16 + g * 4 + r;  // local row 0..127
                vred[rl * 2 + wc] = v;
                dred[rl * 2 + wc] = d;
            }
        }
    __syncthreads();

    float lsum = 0.f;
    if (tid < 128) {
        const float vv = vred[tid * 2] + vred[tid * 2 + 1];
        const float dd = dred[tid * 2] + dred[tid * 2 + 1];
        lsum = logf(vv) - dd;
    }
#pragma unroll
    for (int m = 1; m < 64; m <<= 1) lsum += __shfl_xor(lsum, m);
    __syncthreads();
    float* red = reinterpret_cast<float*>(lds);
    if (lane == 0) red[wave] = lsum;  // waves 2,3 contribute 0
    __syncthreads();
    if (tid == 0) partials[blockIdx.x] = red[0] + red[1] + red[2] + red[3];
}

// ---------------- Pass 3: final deterministic reduce ----------------
__global__ __launch_bounds__(256) void final_reduce(const float* __restrict__ partials,
                                                    float* __restrict__ out) {
    const int t = threadIdx.x;
    float v = partials[t];
#pragma unroll
    for (int m = 1; m < 64; m <<= 1) v += __shfl_xor(v, m);
    __shared__ float red[4];
    if ((t & 63) == 0) red[t >> 6] = v;
    __syncthreads();
    if (t == 0) out[0] = (red[0] + red[1] + red[2] + red[3]) * (1.0f / 32768.0f);
}

extern "C" void kernel_launch(void* const* d_in, const int* in_sizes, int n_in,
                              void* d_out, int out_size, void* d_ws, size_t ws_size,
                              hipStream_t stream) {
    const float* vis = (const float*)d_in[0];
    const float* txt = (const float*)d_in[1];

    unsigned short* Vn = (unsigned short*)d_ws;                      // 64*512*256 bf16 = 16 MB
    unsigned short* Tn = Vn + (size_t)BB * CC * DD;                  // +16 MB
    float* partials    = (float*)(Tn + (size_t)BB * CC * DD);        // 256 floats
    float* out         = (float*)d_out;

    // allow 128 KiB dynamic LDS (host-side attribute set; not a stream op)
    hipFuncSetAttribute((const void*)gemm_loss, hipFuncAttributeMaxDynamicSharedMemorySize,
                        131072);

    norm_rows<<<8192, 256, 0, stream>>>(vis, Vn);
    norm_rows<<<8192, 256, 0, stream>>>(txt, Tn);
    gemm_loss<<<256, 256, 131072, stream>>>(Vn, Tn, partials);
    final_reduce<<<1, 256, 0, stream>>>(partials, out);
}

// Round 3
// 43.952 us; speedup vs baseline: 1.0522x; 1.0522x over previous
//
#include <hip/hip_runtime.h>
#include <hip/hip_bf16.h>

// Problem constants
#define BB 64
#define CC 512
#define DD 256
// loss = mean_{b,c} [ log(sum_k exp(2*S_bck)) - 2*S_bcc ],  S = Vn . Tn^T (rows L2-normalized)

typedef __attribute__((ext_vector_type(8))) short bf16x8;  // 8 bf16 = 4 VGPRs
typedef __attribute__((ext_vector_type(4))) float f32x4;

__device__ inline short f2bf(float f) {
    union { __hip_bfloat16 h; short s; } cv;
    cv.h = __float2bfloat16(f);
    return cv.s;
}

// ---------------- Fused kernel: normalize (on the fly) + batched GEMM + loss ----------------
// 256 blocks, one per (batch b, row-block rb of 128 rows). Inputs are RAW fp32; each block
// normalizes rows as it stages them (8 lanes per row, shfl reduce), writing bf16 into
// XOR-swizzled LDS. A (128x256) staged once then cached in registers (a[4][8], 128 VGPR).
// B (T rows) double-buffered 2x32KB in 64-row tiles, 8 iterations, with async reg-staging:
// issue global loads -> MFMA on current tile -> normalize+ds_write next tile -> 1 barrier.
__global__ __launch_bounds__(256, 1) void gemm_loss(const float* __restrict__ V,
                                                    const float* __restrict__ T,
                                                    float* __restrict__ partials) {
    extern __shared__ char lds[];
    char* As  = lds;                    // 128 rows x 512 B (swizzled bf16)
    char* Bs0 = lds + 65536;            // 64 rows x 512 B
    char* Bs1 = lds + 65536 + 32768;    // 64 rows x 512 B

    // XCD-aware remap: co-locate a batch's 4 rb-blocks on one XCD (T panel L2 reuse).
    const int i0 = blockIdx.x;
    const int b  = (i0 & 7) * 8 + (i0 >> 5);   // bijective over 0..63
    const int rb = (i0 >> 3) & 3;

    const int tid  = threadIdx.x;
    const int lane = tid & 63;
    const int wave = tid >> 6;
    const int wr = wave >> 1;   // 2x2 wave grid over 128 rows x 64 cols per tile
    const int wc = wave & 1;
    const int g  = lane >> 4;   // k-group 0..3
    const int ln = lane & 15;

    const float* gV = V + (size_t)b * (CC * DD) + (size_t)rb * 128 * DD;
    const float* gT = T + (size_t)b * (CC * DD);

    const int rrow = tid >> 3;        // row within a 32-row staging group (8 threads/row)
    const int ecol = (tid & 7) * 32;  // this thread's 32 contiguous elements of the row

    // ---------- Prologue: stage A with fused L2-normalization ----------
    {
        float4 ar[4][8];
#pragma unroll
        for (int p = 0; p < 4; ++p) {
            const float4* src =
                reinterpret_cast<const float4*>(gV + (size_t)(p * 32 + rrow) * DD + ecol);
#pragma unroll
            for (int q = 0; q < 8; ++q) ar[p][q] = src[q];
        }
#pragma unroll
        for (int p = 0; p < 4; ++p) {
            float ss = 0.f;
#pragma unroll
            for (int q = 0; q < 8; ++q)
                ss += ar[p][q].x * ar[p][q].x + ar[p][q].y * ar[p][q].y +
                      ar[p][q].z * ar[p][q].z + ar[p][q].w * ar[p][q].w;
            ss += __shfl_xor(ss, 1);
            ss += __shfl_xor(ss, 2);
            ss += __shfl_xor(ss, 4);   // 8 lanes of this row
            const float rinv = 1.0f / fmaxf(sqrtf(ss), 1e-12f);
            const int row = p * 32 + rrow;
            char* dstrow  = As + row * 512;
            const int sw  = (row & 7) << 4;
#pragma unroll
            for (int q2 = 0; q2 < 4; ++q2) {
                const float4 v0 = ar[p][2 * q2], v1 = ar[p][2 * q2 + 1];
                bf16x8 o;
                o[0] = f2bf(v0.x * rinv); o[1] = f2bf(v0.y * rinv);
                o[2] = f2bf(v0.z * rinv); o[3] = f2bf(v0.w * rinv);
                o[4] = f2bf(v1.x * rinv); o[5] = f2bf(v1.y * rinv);
                o[6] = f2bf(v1.z * rinv); o[7] = f2bf(v1.w * rinv);
                const int bc = ecol * 2 + q2 * 16;   // byte offset within row
                *reinterpret_cast<bf16x8*>(dstrow + (bc ^ sw)) = o;
            }
        }
    }
    // ---------- Prologue: stage B tile 0 (same fused normalize) ----------
    {
#pragma unroll
        for (int p = 0; p < 2; ++p) {
            const float4* src =
                reinterpret_cast<const float4*>(gT + (size_t)(p * 32 + rrow) * DD + ecol);
            float4 x[8];
#pragma unroll
            for (int q = 0; q < 8; ++q) x[q] = src[q];
            float ss = 0.f;
#pragma unroll
            for (int q = 0; q < 8; ++q)
                ss += x[q].x * x[q].x + x[q].y * x[q].y + x[q].z * x[q].z + x[q].w * x[q].w;
            ss += __shfl_xor(ss, 1);
            ss += __shfl_xor(ss, 2);
            ss += __shfl_xor(ss, 4);
            const float rinv = 1.0f / fmaxf(sqrtf(ss), 1e-12f);
            const int row = p * 32 + rrow;
            char* dstrow  = Bs0 + row * 512;
            const int sw  = (row & 7) << 4;
#pragma unroll
            for (int q2 = 0; q2 < 4; ++q2) {
                const float4 v0 = x[2 * q2], v1 = x[2 * q2 + 1];
                bf16x8 o;
                o[0] = f2bf(v0.x * rinv); o[1] = f2bf(v0.y * rinv);
                o[2] = f2bf(v0.z * rinv); o[3] = f2bf(v0.w * rinv);
                o[4] = f2bf(v1.x * rinv); o[5] = f2bf(v1.y * rinv);
                o[6] = f2bf(v1.z * rinv); o[7] = f2bf(v1.w * rinv);
                const int bc = ecol * 2 + q2 * 16;
                *reinterpret_cast<bf16x8*>(dstrow + (bc ^ sw)) = o;
            }
        }
    }
    __syncthreads();

    // ---------- Cache A fragments in registers (A never re-read from LDS) ----------
    bf16x8 a[4][8];
#pragma unroll
    for (int i = 0; i < 4; ++i) {
        const int row  = wr * 64 + i * 16 + ln;
        const char* rp = As + row * 512;
        const int sw   = (row & 7) << 4;
#pragma unroll
        for (int kk = 0; kk < 8; ++kk)
            a[i][kk] = *reinterpret_cast<const bf16x8*>(rp + ((kk * 64 + g * 16) ^ sw));
    }

    float rs[4][4];  // rowsum of exp(2S) over this wave's columns
    float dg[4][4];  // diagonal 2*S term
#pragma unroll
    for (int i = 0; i < 4; ++i)
#pragma unroll
        for (int r = 0; r < 4; ++r) { rs[i][r] = 0.f; dg[i][r] = 0.f; }

    const f32x4 fzero = {0.f, 0.f, 0.f, 0.f};
    float4 br[2][8];  // async-staged next B tile (fp32)
    int cur = 0;

    for (int ct = 0; ct < 8; ++ct) {
        // ---- issue next tile's global loads (latency hides under MFMA) ----
        if (ct < 7) {
            const float* gB = gT + (size_t)(ct + 1) * 64 * DD;
#pragma unroll
            for (int p = 0; p < 2; ++p) {
                const float4* src =
                    reinterpret_cast<const float4*>(gB + (size_t)(p * 32 + rrow) * DD + ecol);
#pragma unroll
                for (int q = 0; q < 8; ++q) br[p][q] = src[q];
            }
        }

        // ---- MFMA on current tile ----
        char* Bc = cur ? Bs1 : Bs0;
        f32x4 acc[4][2];
#pragma unroll
        for (int i = 0; i < 4; ++i)
#pragma unroll
            for (int j = 0; j < 2; ++j) acc[i][j] = fzero;

#pragma unroll
        for (int kk = 0; kk < 8; ++kk) {
            bf16x8 bb[2];
#pragma unroll
            for (int j = 0; j < 2; ++j) {
                const int row = wc * 32 + j * 16 + ln;
                bb[j] = *reinterpret_cast<const bf16x8*>(
                    Bc + row * 512 + (((kk * 64 + g * 16)) ^ ((row & 7) << 4)));
            }
#pragma unroll
            for (int i = 0; i < 4; ++i)
#pragma unroll
                for (int j = 0; j < 2; ++j)
                    acc[i][j] =
                        __builtin_amdgcn_mfma_f32_16x16x32_bf16(a[i][kk], bb[j], acc[i][j], 0, 0, 0);
        }

        // ---- fused epilogue: exp(2*S) partial rowsum + diagonal grab ----
        const int gcb = ct * 64 + wc * 32;
#pragma unroll
        for (int i = 0; i < 4; ++i) {
            const int grow = rb * 128 + wr * 64 + i * 16 + g * 4;  // + r
#pragma unroll
            for (int j = 0; j < 2; ++j) {
                const int gcol = gcb + j * 16 + ln;
#pragma unroll
                for (int r = 0; r < 4; ++r) {
                    const float s2 = acc[i][j][r] * 2.0f;  // sim / TEMPERATURE
                    rs[i][r] += __expf(s2);
                    if (gcol == grow + r) dg[i][r] += s2;
                }
            }
        }

        // ---- normalize staged regs, write next tile into the other buffer ----
        if (ct < 7) {
            char* Bn = cur ? Bs0 : Bs1;
#pragma unroll
            for (int p = 0; p < 2; ++p) {
                float ss = 0.f;
#pragma unroll
                for (int q = 0; q < 8; ++q)
                    ss += br[p][q].x * br[p][q].x + br[p][q].y * br[p][q].y +
                          br[p][q].z * br[p][q].z + br[p][q].w * br[p][q].w;
                ss += __shfl_xor(ss, 1);
                ss += __shfl_xor(ss, 2);
                ss += __shfl_xor(ss, 4);
                const float rinv = 1.0f / fmaxf(sqrtf(ss), 1e-12f);
                const int row = p * 32 + rrow;
                char* dstrow  = Bn + row * 512;
                const int sw  = (row & 7) << 4;
#pragma unroll
                for (int q2 = 0; q2 < 4; ++q2) {
                    const float4 v0 = br[p][2 * q2], v1 = br[p][2 * q2 + 1];
                    bf16x8 o;
                    o[0] = f2bf(v0.x * rinv); o[1] = f2bf(v0.y * rinv);
                    o[2] = f2bf(v0.z * rinv); o[3] = f2bf(v0.w * rinv);
                    o[4] = f2bf(v1.x * rinv); o[5] = f2bf(v1.y * rinv);
                    o[6] = f2bf(v1.z * rinv); o[7] = f2bf(v1.w * rinv);
                    const int bc = ecol * 2 + q2 * 16;
                    *reinterpret_cast<bf16x8*>(dstrow + (bc ^ sw)) = o;
                }
            }
        }
        __syncthreads();
        cur ^= 1;
    }

    // ---- per-row completion: combine the two wc-waves' exp-sums BEFORE log ----
    float* vred = reinterpret_cast<float*>(lds);   // [128][2], reuses dead As
    float* dred = vred + 256;                      // [128][2]
    float* red  = vred + 512;                      // [4]
#pragma unroll
    for (int i = 0; i < 4; ++i)
#pragma unroll
        for (int r = 0; r < 4; ++r) {
            float v = rs[i][r];
            float d = dg[i][r];
#pragma unroll
            for (int m = 1; m < 16; m <<= 1) {  // reduce the 16 column-lanes
                v += __shfl_xor(v, m);
                d += __shfl_xor(d, m);
            }
            if (ln == 0) {
                const int rl = wr * 64 + i * 16 + g * 4 + r;  // local row 0..127
                vred[rl * 2 + wc] = v;
                dred[rl * 2 + wc] = d;
            }
        }
    __syncthreads();

    float lsum = 0.f;
    if (tid < 128) {
        const float vv = vred[tid * 2] + vred[tid * 2 + 1];
        const float dd = dred[tid * 2] + dred[tid * 2 + 1];
        lsum = logf(vv) - dd;
    }
#pragma unroll
    for (int m = 1; m < 64; m <<= 1) lsum += __shfl_xor(lsum, m);
    if (lane == 0) red[wave] = lsum;  // waves 2,3 contribute 0
    __syncthreads();
    if (tid == 0) partials[blockIdx.x] = red[0] + red[1] + red[2] + red[3];
}

// ---------------- Final deterministic reduce ----------------
__global__ __launch_bounds__(256) void final_reduce(const float* __restrict__ partials,
                                                    float* __restrict__ out) {
    const int t = threadIdx.x;
    float v = partials[t];
#pragma unroll
    for (int m = 1; m < 64; m <<= 1) v += __shfl_xor(v, m);
    __shared__ float red[4];
    if ((t & 63) == 0) red[t >> 6] = v;
    __syncthreads();
    if (t == 0) out[0] = (red[0] + red[1] + red[2] + red[3]) * (1.0f / 32768.0f);
}

extern "C" void kernel_launch(void* const* d_in, const int* in_sizes, int n_in,
                              void* d_out, int out_size, void* d_ws, size_t ws_size,
                              hipStream_t stream) {
    const float* vis = (const float*)d_in[0];
    const float* txt = (const float*)d_in[1];

    float* partials = (float*)d_ws;   // 256 floats
    float* out      = (float*)d_out;

    hipFuncSetAttribute((const void*)gemm_loss, hipFuncAttributeMaxDynamicSharedMemorySize,
                        131072);

    gemm_loss<<<256, 256, 131072, stream>>>(vis, txt, partials);
    final_reduce<<<1, 256, 0, stream>>>(partials, out);
}